// Round 18
// baseline (34.217 us; speedup 1.0000x reference)
//
#include <hip/hip_runtime.h>
#include <cfloat>

#define B_ 32
#define N_ 1000
#define K_ 10
#define H_ 128
#define C_ 2
#define NFEAT 43
#define QPB 32      // queries per block
#define TPQ 8       // lanes per query (proven optimum)
#define G_ 16
#define CW (1.0f / 16.0f)
#define RING0 2     // 5x5 cell box

// ws layout (bytes): [0,22016) Meff only (sort is fused into conv kernel)
#define WS_MEFF   0
#define WS_NEED   22016

typedef float v2f __attribute__((ext_vector_type(2)));

#if defined(__has_builtin)
#if __has_builtin(__builtin_elementwise_fma)
#define HAVE_EW_FMA 1
#endif
#endif

// ---------------------------------------------------------------------------
// Kernel A: fused affine map M[43][128] (folds Wx,Wy,W1,W2,biases).
// ---------------------------------------------------------------------------
__global__ __launch_bounds__(H_) void build_meff(
    const float* __restrict__ Wx, const float* __restrict__ bx,
    const float* __restrict__ Wy, const float* __restrict__ by,
    const float* __restrict__ W1, const float* __restrict__ b1,
    const float* __restrict__ W2, const float* __restrict__ b2,
    float* __restrict__ M) {
  const int r = blockIdx.x;
  const int g = threadIdx.x;
  float acc = 0.f;
  if (r < 40) {
    const int rp = (r < 20) ? r : r - 20;
    const float* W = (r < 20) ? Wx : Wy;
    const int k = rp >> 1;
    const int c = rp & 1;
    const float* Wcol = W + c * K_ + k;     // h-stride = C_*K_
    for (int h = 0; h < H_; ++h)
      acc = fmaf(Wcol[h * C_ * K_], W2[h * H_ + g], acc);
  } else if (r < 42) {
    acc = W1[(r - 40) * H_ + g];
  } else {
    for (int h = 0; h < H_; ++h)
      acc = fmaf(bx[h] + by[h], W2[h * H_ + g], acc);
    acc += b1[g] + b2[g];
  }
  M[r * H_ + g] = acc;
}

// ---------------------------------------------------------------------------
// shuffle helper
// ---------------------------------------------------------------------------
__device__ __forceinline__ unsigned long long shflx64(unsigned long long v, int msk) {
  const unsigned lo = __shfl_xor((unsigned)(v & 0xffffffffull), msk, 64);
  const unsigned hi = __shfl_xor((unsigned)(v >> 32), msk, 64);
  return ((unsigned long long)hi << 32) | lo;
}

// branchless rank-insert (u64 key = (d2,orig,spos) => exact lax.top_k order;
// key order depends only on (d2, orig) — spos is a block-local LDS address)
#define INSERT_LDS(j)                                                          \
  {                                                                            \
    const float4 pk = spk[(j)];                                                \
    const float dx = __fsub_rn(px, pk.x);                                      \
    const float dy = __fsub_rn(py, pk.y);                                      \
    const float dd = __fadd_rn(__fmul_rn(dx, dx), __fmul_rn(dy, dy));          \
    const unsigned long long key =                                             \
        ((unsigned long long)__float_as_uint(dd) << 32) |                      \
        (unsigned)__float_as_int(pk.z);                                        \
    bool c[K_];                                                                \
    _Pragma("unroll") for (int kk = 0; kk < K_; ++kk) c[kk] = key < bk[kk];    \
    _Pragma("unroll") for (int kk = K_ - 1; kk >= 1; --kk)                     \
        bk[kk] = c[kk - 1] ? bk[kk - 1] : (c[kk] ? key : bk[kk]);              \
    bk[0] = c[0] ? key : bk[0];                                                \
  }

// Fused merge+gather: 10 rounds of cross-lane (8-lane) min of the sorted
// list heads; winner popped branchlessly; winner's coords broadcast-read
// from LDS straight into feat[] (static indices). Returns the 10th key.
#define MERGE_GATHER(tenth_out)                                                \
  {                                                                            \
    _Pragma("unroll") for (int s2 = 0; s2 < K_; ++s2) {                        \
      unsigned long long m = bk[0];                                            \
      unsigned long long o = shflx64(m, 1); m = (o < m) ? o : m;               \
      o = shflx64(m, 2); m = (o < m) ? o : m;                                  \
      o = shflx64(m, 4); m = (o < m) ? o : m;                                  \
      const bool pop = (bk[0] == m);                                           \
      _Pragma("unroll") for (int k2 = 0; k2 < K_ - 1; ++k2)                    \
          bk[k2] = pop ? bk[k2 + 1] : bk[k2];                                  \
      bk[K_ - 1] = pop ? ~0ull : bk[K_ - 1];                                   \
      const int spos = min((int)(m & 0xffffull), N_ - 1);                      \
      const float4 c4 = spk[spos];                                             \
      feat[2 * s2]          = c4.x;                                            \
      feat[2 * s2 + 1]      = c4.y;                                            \
      feat[20 + 2 * s2]     = c4.x;                                            \
      feat[20 + 2 * s2 + 1] = c4.y;                                            \
      if (s2 == K_ - 1) (tenth_out) = m;                                       \
    }                                                                          \
  }

// ---------------------------------------------------------------------------
// Fused kernel: per-block in-LDS counting sort (removes the serialized prep
// sort), then champion grid-pruned exact KNN + merge-gather + pk_fma affine.
// Queries indexed by ORIGINAL point index (per-block scatter order is
// nondeterministic, but keys order by (d2, orig) => output deterministic).
// LDS: spk 16K + cstart 1K + smem 22K (hist/cur alias smem) = 39.1 KB.
// NOTE: no min-waves hint > 4 — VGPR caps below demand spill wholesale
// (R6/R8: WRITE_SIZE 16->76/108 MB).
// ---------------------------------------------------------------------------
__global__ __launch_bounds__(QPB * TPQ, 4) void conv_knn(
    const float* __restrict__ x, const float* __restrict__ Meff,
    float* __restrict__ out) {
  __shared__ __align__(16) float4 spk[N_];          // 16 KB (x, y, keybits, 0)
  __shared__ int    cstart[G_ * G_ + 1];            // 1 KB
  __shared__ __align__(16) float smem[NFEAT * H_];  // 22 KB: hist/cur, later M
  int* hist = (int*)smem;          // [256]  (aliases M region; M loads later)
  int* cur  = ((int*)smem) + 256;  // [256]

  const int b = blockIdx.y, tid = threadIdx.x;
  const int q = tid >> 3, t = tid & 7;
  const int n = blockIdx.x * QPB + q;   // query = ORIGINAL index
  const bool valid = (n < N_);

  const float2* xb = (const float2*)(x + (size_t)b * N_ * C_);

  // ---- stage up to 4 points/thread in registers + cell ids ----
  float2 sp[4];
  int    sc[4];
#pragma unroll
  for (int k = 0; k < 4; ++k) {
    const int i = tid + k * 256;
    if (i < N_) {
      const float2 v = xb[i];
      sp[k] = v;
      const int cxx = min(G_ - 1, max(0, (int)(v.x * (float)G_)));
      const int cyy = min(G_ - 1, max(0, (int)(v.y * (float)G_)));
      sc[k] = cyy * G_ + cxx;
    } else {
      sc[k] = -1;
    }
  }
  hist[tid] = 0;
  __syncthreads();
#pragma unroll
  for (int k = 0; k < 4; ++k)
    if (sc[k] >= 0) atomicAdd(&hist[sc[k]], 1);
  __syncthreads();

  // ---- single-wave exclusive scan of hist[256] (lane l owns 4 cells) ----
  if (tid < 64) {
    const int l = tid;
    const int h0 = hist[4 * l], h1 = hist[4 * l + 1];
    const int h2 = hist[4 * l + 2], h3 = hist[4 * l + 3];
    const int T = h0 + h1 + h2 + h3;
    int v = T;
#pragma unroll
    for (int off = 1; off < 64; off <<= 1) {
      const int u = __shfl_up(v, off, 64);
      v += (l >= off) ? u : 0;
    }
    const int E = v - T;
    cur[4 * l] = E;
    cur[4 * l + 1] = E + h0;
    cur[4 * l + 2] = E + h0 + h1;
    cur[4 * l + 3] = E + h0 + h1 + h2;
    cstart[4 * l] = E;
    cstart[4 * l + 1] = E + h0;
    cstart[4 * l + 2] = E + h0 + h1;
    cstart[4 * l + 3] = E + h0 + h1 + h2;
    if (l == 63) cstart[G_ * G_] = N_;
  }
  __syncthreads();

  // ---- scatter into sorted LDS spk (block-local positions) ----
#pragma unroll
  for (int k = 0; k < 4; ++k) {
    if (sc[k] >= 0) {
      const int i = tid + k * 256;
      const int pos = atomicAdd(&cur[sc[k]], 1);
      spk[pos] = make_float4(sp[k].x, sp[k].y,
                             __int_as_float((i << 16) | pos), 0.f);
    }
  }
  __syncthreads();

  // ---- query coords from global (wave-broadcast across a query's 8 lanes) ----
  float px = 0.f, py = 0.f;
  int cx = 0, cy = 0;
  if (valid) {
    const float2 v = xb[n];
    px = v.x; py = v.y;
    cx = min(G_ - 1, max(0, (int)(px * (float)G_)));
    cy = min(G_ - 1, max(0, (int)(py * (float)G_)));
  }

  unsigned long long bk[K_];
#pragma unroll
  for (int k = 0; k < K_; ++k) bk[k] = ~0ull;

  // ---- single-pass 5x5 box scan, 8-way sliced per query ----
  const int X0 = max(cx - RING0, 0), X1 = min(cx + RING0, G_ - 1);
  const int Y0 = max(cy - RING0, 0), Y1 = min(cy + RING0, G_ - 1);
  if (valid) {
    for (int yy = Y0; yy <= Y1; ++yy) {
      const int s0 = cstart[yy * G_ + X0];
      const int s1 = cstart[yy * G_ + X1 + 1];
      for (int j = s0 + t; j < s1; j += TPQ) INSERT_LDS(j);
    }
  }

  // ---- fused merge + gather (unguarded: all 64 lanes shuffle) ----
  float feat[NFEAT];
  unsigned long long tenth = ~0ull;
  MERGE_GATHER(tenth);

  // ---- exact termination test (identical across a query's 8 lanes) ----
  bool done = true;
  if (valid) {
    const bool have10 = (tenth != ~0ull);
    const float tau = __uint_as_float((unsigned)(tenth >> 32));
    float R = 1e30f;
    if (X0 > 0)      R = fminf(R, px - (float)X0 * CW);
    if (X1 < G_ - 1) R = fminf(R, (float)(X1 + 1) * CW - px);
    if (Y0 > 0)      R = fminf(R, py - (float)Y0 * CW);
    if (Y1 < G_ - 1) R = fminf(R, (float)(Y1 + 1) * CW - py);
    const bool fullg = (X0 == 0) && (X1 == G_ - 1) && (Y0 == 0) && (Y1 == G_ - 1);
    const float Rs = R - 1e-6f;   // margin vs. cell-assignment rounding
    done = fullg || (have10 && Rs > 0.f && tau < Rs * Rs);
  }

  // ---- rare exact retry: full scan + re-merge (query-uniform predicate) ----
  if (__syncthreads_and(done ? 1 : 0) == 0) {
    const bool redo = valid && !done;
    if (redo) {
#pragma unroll
      for (int k = 0; k < K_; ++k) bk[k] = ~0ull;
      for (int j = t; j < N_; j += TPQ) INSERT_LDS(j);
    }
    if (redo) {          // all 8 lanes of a redo query enter together
      unsigned long long tenth2;
      MERGE_GATHER(tenth2);
    }
  }

  // ---- load M into LDS (overwrites hist/cur — all uses complete) ----
  __syncthreads();
  for (int i = tid; i < NFEAT * H_; i += QPB * TPQ) smem[i] = Meff[i];

  // ---- in-place stable bubble sorts on feat (all lanes redundant) ----
  if (valid) {
    // sort pairs (feat[2k],feat[2k+1]) by x  (strict swap => stable)
#pragma unroll
    for (int p = 0; p < K_ - 1; ++p) {
#pragma unroll
      for (int u = 0; u < K_ - 1 - p; ++u) {
        const bool sw = feat[2 * u + 2] < feat[2 * u];
        const float ax = feat[2 * u], ay = feat[2 * u + 1];
        feat[2 * u]     = sw ? feat[2 * u + 2] : ax;
        feat[2 * u + 1] = sw ? feat[2 * u + 3] : ay;
        feat[2 * u + 2] = sw ? ax : feat[2 * u + 2];
        feat[2 * u + 3] = sw ? ay : feat[2 * u + 3];
      }
    }
    // sort pairs (feat[20+2k],feat[20+2k+1]) by y
#pragma unroll
    for (int p = 0; p < K_ - 1; ++p) {
#pragma unroll
      for (int u = 0; u < K_ - 1 - p; ++u) {
        const int e = 20 + 2 * u;
        const bool sw = feat[e + 3] < feat[e + 1];
        const float ax = feat[e], ay = feat[e + 1];
        feat[e]     = sw ? feat[e + 2] : ax;
        feat[e + 1] = sw ? feat[e + 3] : ay;
        feat[e + 2] = sw ? ax : feat[e + 2];
        feat[e + 3] = sw ? ay : feat[e + 3];
      }
    }
    feat[40] = px;
    feat[41] = py;
    feat[42] = 1.f;
  }
  __syncthreads();

  // ---- fused affine: float4 LDS reads, g = j*32 + 4t (8 lanes span all 32
  // banks, queries broadcast); packed v_pk_fma_f32 accumulate;
  // 128B-contiguous stores directly to row n ----
  if (valid) {
    float* op = out + ((size_t)(b * N_ + n)) * H_;
    const float4* M4 = (const float4*)smem;   // row r = 32 float4
#pragma unroll
    for (int j = 0; j < 4; ++j) {
      v2f a0 = {0.f, 0.f}, a1 = {0.f, 0.f};
#pragma unroll
      for (int r = 0; r < NFEAT; ++r) {
        const float4 m = M4[r * 32 + j * 8 + t];
        const float f = feat[r];
#ifdef HAVE_EW_FMA
        const v2f ff = {f, f};
        const v2f m0 = {m.x, m.y};
        const v2f m1 = {m.z, m.w};
        a0 = __builtin_elementwise_fma(ff, m0, a0);
        a1 = __builtin_elementwise_fma(ff, m1, a1);
#else
        a0.x = fmaf(f, m.x, a0.x);
        a0.y = fmaf(f, m.y, a0.y);
        a1.x = fmaf(f, m.z, a1.x);
        a1.y = fmaf(f, m.w, a1.y);
#endif
      }
      *(float4*)&op[j * 32 + 4 * t] = make_float4(a0.x, a0.y, a1.x, a1.y);
    }
  }
}
#undef INSERT_LDS
#undef MERGE_GATHER

// ---------------------------------------------------------------------------
// No-workspace fallback (round-2 kernel).
// ---------------------------------------------------------------------------
#define LSTRIDE 170
__global__ __launch_bounds__(256, 4) void conv_emb_fb(
    const float* __restrict__ x, const float* __restrict__ Meff,
    float* __restrict__ out) {
  __shared__ float2 pts[N_];
  __shared__ float  smem[NFEAT * H_];
  __shared__ int    midx[32 * K_];

  const int b   = blockIdx.y;
  const int tid = threadIdx.x;
  const int q   = tid >> 3;
  const int t   = tid & 7;
  const int n   = blockIdx.x * 32 + q;
  const bool valid = (n < N_);

  const float2* xb = (const float2*)(x + (size_t)b * N_ * C_);
  for (int i = tid; i < N_; i += 256) pts[i] = xb[i];
  __syncthreads();

  float px = 0.f, py = 0.f;
  if (valid) { px = pts[n].x; py = pts[n].y; }

  float bd[K_]; int bi[K_];
#pragma unroll
  for (int k = 0; k < K_; ++k) { bd[k] = FLT_MAX; bi[k] = 0; }

#pragma unroll 2
  for (int m = 0; m < N_ / 8; ++m) {
    const int j = t + m * 8;
    const float2 p = pts[j];
    const float dx = __fsub_rn(px, p.x);
    const float dy = __fsub_rn(py, p.y);
    const float d  = __fadd_rn(__fmul_rn(dx, dx), __fmul_rn(dy, dy));
    bool c[K_];
#pragma unroll
    for (int s = 0; s < K_; ++s) c[s] = d < bd[s];
#pragma unroll
    for (int s = K_ - 1; s >= 1; --s) {
      bd[s] = c[s - 1] ? bd[s - 1] : (c[s] ? d : bd[s]);
      bi[s] = c[s - 1] ? bi[s - 1] : (c[s] ? j : bi[s]);
    }
    bd[0] = c[0] ? d : bd[0];
    bi[0] = c[0] ? j : bi[0];
  }

  const int lbase = q * LSTRIDE + t * 2 * K_;
#pragma unroll
  for (int e = 0; e < K_; ++e) {
    smem[lbase + 2 * e]     = bd[e];
    smem[lbase + 2 * e + 1] = __int_as_float(bi[e]);
  }
  __syncthreads();

  if (t == 0 && valid) {
    int cc[8];
#pragma unroll
    for (int tt = 0; tt < 8; ++tt) cc[tt] = 0;
    const int mb = q * LSTRIDE;
#pragma unroll
    for (int s = 0; s < K_; ++s) {
      float bdv = FLT_MAX; int biv = 0x7fffffff; int bt = 0;
#pragma unroll
      for (int tt = 0; tt < 8; ++tt) {
        const int off = mb + tt * 2 * K_ + cc[tt] * 2;
        const float hd = smem[off];
        const int   hi = __float_as_int(smem[off + 1]);
        const bool take = (hd < bdv) || ((hd == bdv) && (hi < biv));
        bdv = take ? hd : bdv;
        biv = take ? hi : biv;
        bt  = take ? tt : bt;
      }
      midx[q * K_ + s] = biv;
#pragma unroll
      for (int tt = 0; tt < 8; ++tt) cc[tt] += (bt == tt) ? 1 : 0;
    }
  }
  __syncthreads();

  int ridx[K_];
  if (valid) {
#pragma unroll
    for (int k = 0; k < K_; ++k) ridx[k] = midx[q * K_ + k];
  }
  for (int i = tid; i < NFEAT * H_; i += 256) smem[i] = Meff[i];

  float feat[NFEAT];
  if (valid) {
#pragma unroll
    for (int k = 0; k < K_; ++k) {
      const float2 c = pts[ridx[k]];
      feat[2 * k]          = c.x;
      feat[2 * k + 1]      = c.y;
      feat[20 + 2 * k]     = c.x;
      feat[20 + 2 * k + 1] = c.y;
    }
#pragma unroll
    for (int p = 0; p < K_ - 1; ++p) {
#pragma unroll
      for (int u = 0; u < K_ - 1 - p; ++u) {
        const bool sw = feat[2 * u + 2] < feat[2 * u];
        const float ax = feat[2 * u], ay = feat[2 * u + 1];
        feat[2 * u]     = sw ? feat[2 * u + 2] : ax;
        feat[2 * u + 1] = sw ? feat[2 * u + 3] : ay;
        feat[2 * u + 2] = sw ? ax : feat[2 * u + 2];
        feat[2 * u + 3] = sw ? ay : feat[2 * u + 3];
      }
    }
#pragma unroll
    for (int p = 0; p < K_ - 1; ++p) {
#pragma unroll
      for (int u = 0; u < K_ - 1 - p; ++u) {
        const int e = 20 + 2 * u;
        const bool sw = feat[e + 3] < feat[e + 1];
        const float ax = feat[e], ay = feat[e + 1];
        feat[e]     = sw ? feat[e + 2] : ax;
        feat[e + 1] = sw ? feat[e + 3] : ay;
        feat[e + 2] = sw ? ax : feat[e + 2];
        feat[e + 3] = sw ? ay : feat[e + 3];
      }
    }
    feat[40] = px;
    feat[41] = py;
    feat[42] = 1.f;
  }
  __syncthreads();

  if (valid) {
    float* op = out + ((size_t)(b * N_ + n)) * H_;
#pragma unroll 2
    for (int gi = 0; gi < H_ / 8; ++gi) {
      const int g = gi * 8 + t;
      float acc = 0.f;
#pragma unroll
      for (int r = 0; r < NFEAT; ++r)
        acc = fmaf(feat[r], smem[r * H_ + g], acc);
      op[g] = acc;
    }
  }
}

extern "C" void kernel_launch(void* const* d_in, const int* in_sizes, int n_in,
                              void* d_out, int out_size, void* d_ws, size_t ws_size,
                              hipStream_t stream) {
  const float* x  = (const float*)d_in[0];
  const float* Wx = (const float*)d_in[1];
  const float* bx = (const float*)d_in[2];
  const float* by_ = (const float*)d_in[4];
  const float* Wy = (const float*)d_in[3];
  const float* W1 = (const float*)d_in[5];
  const float* b1 = (const float*)d_in[6];
  const float* W2 = (const float*)d_in[7];
  const float* b2 = (const float*)d_in[8];
  float* o = (float*)d_out;

  char* ws = (char*)d_ws;
  float* Meff = (float*)(ws + WS_MEFF);

  build_meff<<<dim3(NFEAT), dim3(H_), 0, stream>>>(Wx, bx, Wy, by_, W1, b1, W2, b2, Meff);

  if (ws_size >= (size_t)WS_NEED) {
    conv_knn<<<dim3((N_ + QPB - 1) / QPB, B_), dim3(QPB * TPQ), 0, stream>>>(x, Meff, o);
  } else {
    conv_emb_fb<<<dim3((N_ + 31) / 32, B_), dim3(256), 0, stream>>>(x, Meff, o);
  }
}

// Round 19
// 32.348 us; speedup vs baseline: 1.0578x; 1.0578x over previous
//
#include <hip/hip_runtime.h>
#include <cfloat>

#define B_ 32
#define N_ 1000
#define K_ 10
#define H_ 128
#define C_ 2
#define NFEAT 43
#define QPB 32      // queries per block
#define TPQ 8       // lanes per query (proven optimum; waves are grid-invariant)
#define G_ 16
#define CW (1.0f / 16.0f)
#define RING0 2     // 5x5 cell box

// ws layout (bytes): [0,22016) Meff | [22016,534016) spk float4
//                    | [534016,566912) cellstart int
#define WS_MEFF   0
#define WS_SPK    22016
#define WS_CSTART 534016
#define WS_NEED   566912

typedef float v2f __attribute__((ext_vector_type(2)));

#if defined(__has_builtin)
#if __has_builtin(__builtin_elementwise_fma)
#define HAVE_EW_FMA 1
#endif
#endif

// ---------------------------------------------------------------------------
// meff row computation (shared by prep and standalone build_meff)
// ---------------------------------------------------------------------------
__device__ __forceinline__ void meff_row(
    int r, int g, const float* __restrict__ Wx, const float* __restrict__ bx,
    const float* __restrict__ Wy, const float* __restrict__ by,
    const float* __restrict__ W1, const float* __restrict__ b1,
    const float* __restrict__ W2, const float* __restrict__ b2,
    float* __restrict__ M) {
  float acc = 0.f;
  if (r < 40) {
    const int rp = (r < 20) ? r : r - 20;
    const float* W = (r < 20) ? Wx : Wy;
    const int k = rp >> 1;
    const int c = rp & 1;
    const float* Wcol = W + c * K_ + k;
    for (int h = 0; h < H_; ++h)
      acc = fmaf(Wcol[h * C_ * K_], W2[h * H_ + g], acc);
  } else if (r < 42) {
    acc = W1[(r - 40) * H_ + g];
  } else {
    for (int h = 0; h < H_; ++h)
      acc = fmaf(bx[h] + by[h], W2[h * H_ + g], acc);
    acc += b1[g] + b2[g];
  }
  M[r * H_ + g] = acc;
}

__global__ __launch_bounds__(H_) void build_meff(
    const float* __restrict__ Wx, const float* __restrict__ bx,
    const float* __restrict__ Wy, const float* __restrict__ by,
    const float* __restrict__ W1, const float* __restrict__ b1,
    const float* __restrict__ W2, const float* __restrict__ b2,
    float* __restrict__ M) {
  meff_row(blockIdx.x, threadIdx.x, Wx, bx, Wy, by, W1, b1, W2, b2, M);
}

// ---------------------------------------------------------------------------
// Prep (fused): blocks 0..31 = per-batch counting sort (packed float4 out);
// blocks 32..74 = meff rows. Scan = single-wave (2 barriers).
// ---------------------------------------------------------------------------
__global__ __launch_bounds__(256) void prep(
    const float* __restrict__ x,
    const float* __restrict__ Wx, const float* __restrict__ bx,
    const float* __restrict__ Wy, const float* __restrict__ by,
    const float* __restrict__ W1, const float* __restrict__ b1,
    const float* __restrict__ W2, const float* __restrict__ b2,
    float* __restrict__ Meff, float4* __restrict__ spk_g,
    int* __restrict__ cstart_g) {
  const int tid = threadIdx.x;
  if (blockIdx.x >= B_) {
    const int r = blockIdx.x - B_;
    if (tid < H_) meff_row(r, tid, Wx, bx, Wy, by, W1, b1, W2, b2, Meff);
    return;
  }
  const int b = blockIdx.x;
  __shared__ float2 p[N_];
  __shared__ short  cidv[N_];
  __shared__ int    hist[G_ * G_], cur[G_ * G_];

  const float2* xb = (const float2*)(x + (size_t)b * N_ * C_);
  hist[tid] = 0;
  __syncthreads();
  for (int i = tid; i < N_; i += 256) {
    float2 v = xb[i];
    p[i] = v;
    int cxx = min(G_ - 1, max(0, (int)(v.x * (float)G_)));
    int cyy = min(G_ - 1, max(0, (int)(v.y * (float)G_)));
    int c = cyy * G_ + cxx;
    cidv[i] = (short)c;
    atomicAdd(&hist[c], 1);
  }
  __syncthreads();

  // ---- single-wave exclusive scan of hist[256]: lane l owns cells 4l..4l+3
  if (tid < 64) {
    const int l = tid;
    const int h0 = hist[4 * l], h1 = hist[4 * l + 1];
    const int h2 = hist[4 * l + 2], h3 = hist[4 * l + 3];
    const int T = h0 + h1 + h2 + h3;
    int v = T;
#pragma unroll
    for (int off = 1; off < 64; off <<= 1) {
      const int u = __shfl_up(v, off, 64);
      v += (l >= off) ? u : 0;
    }
    const int E = v - T;   // exclusive prefix of this lane's 4-cell group
    const int e0 = E, e1 = E + h0, e2 = E + h0 + h1, e3 = E + h0 + h1 + h2;
    cur[4 * l] = e0; cur[4 * l + 1] = e1; cur[4 * l + 2] = e2; cur[4 * l + 3] = e3;
    int* cs = cstart_g + b * (G_ * G_ + 1);
    cs[4 * l] = e0; cs[4 * l + 1] = e1; cs[4 * l + 2] = e2; cs[4 * l + 3] = e3;
    if (l == 63) cs[G_ * G_] = N_;
  }
  __syncthreads();

  for (int i = tid; i < N_; i += 256) {
    int c = cidv[i];
    int pos = atomicAdd(&cur[c], 1);
    // (x, y, (orig_idx:16|sorted_pos:16) as float bits, 0)
    spk_g[b * N_ + pos] =
        make_float4(p[i].x, p[i].y, __int_as_float((i << 16) | pos), 0.f);
  }
}

// ---------------------------------------------------------------------------
// shuffle helper
// ---------------------------------------------------------------------------
__device__ __forceinline__ unsigned long long shflx64(unsigned long long v, int msk) {
  const unsigned lo = __shfl_xor((unsigned)(v & 0xffffffffull), msk, 64);
  const unsigned hi = __shfl_xor((unsigned)(v >> 32), msk, 64);
  return ((unsigned long long)hi << 32) | lo;
}

// branchless rank-insert (u64 key = (d2,orig,spos) => exact lax.top_k order)
// single packed b128 LDS read per candidate
#define INSERT_LDS(j)                                                          \
  {                                                                            \
    const float4 pk = spk[(j)];                                                \
    const float dx = __fsub_rn(px, pk.x);                                      \
    const float dy = __fsub_rn(py, pk.y);                                      \
    const float dd = __fadd_rn(__fmul_rn(dx, dx), __fmul_rn(dy, dy));          \
    const unsigned long long key =                                             \
        ((unsigned long long)__float_as_uint(dd) << 32) |                      \
        (unsigned)__float_as_int(pk.z);                                        \
    bool c[K_];                                                                \
    _Pragma("unroll") for (int kk = 0; kk < K_; ++kk) c[kk] = key < bk[kk];    \
    _Pragma("unroll") for (int kk = K_ - 1; kk >= 1; --kk)                     \
        bk[kk] = c[kk - 1] ? bk[kk - 1] : (c[kk] ? key : bk[kk]);              \
    bk[0] = c[0] ? key : bk[0];                                                \
  }

// Fused merge+gather: 10 rounds of cross-lane (8-lane) min of the sorted
// list heads; winner popped branchlessly; winner's coords broadcast-read
// from LDS straight into feat[] (static indices). Returns the 10th key.
#define MERGE_GATHER(tenth_out)                                                \
  {                                                                            \
    _Pragma("unroll") for (int s2 = 0; s2 < K_; ++s2) {                        \
      unsigned long long m = bk[0];                                            \
      unsigned long long o = shflx64(m, 1); m = (o < m) ? o : m;               \
      o = shflx64(m, 2); m = (o < m) ? o : m;                                  \
      o = shflx64(m, 4); m = (o < m) ? o : m;                                  \
      const bool pop = (bk[0] == m);                                           \
      _Pragma("unroll") for (int k2 = 0; k2 < K_ - 1; ++k2)                    \
          bk[k2] = pop ? bk[k2 + 1] : bk[k2];                                  \
      bk[K_ - 1] = pop ? ~0ull : bk[K_ - 1];                                   \
      const int spos = min((int)(m & 0xffffull), N_ - 1);                      \
      const float4 c4 = spk[spos];                                             \
      feat[2 * s2]          = c4.x;                                            \
      feat[2 * s2 + 1]      = c4.y;                                            \
      feat[20 + 2 * s2]     = c4.x;                                            \
      feat[20 + 2 * s2 + 1] = c4.y;                                            \
      if (s2 == K_ - 1) (tenth_out) = m;                                       \
    }                                                                          \
  }

// ---------------------------------------------------------------------------
// Kernel C (CHAMPION): grid-pruned exact KNN, packed spk reads, min-reduce
// merge+gather, pk_fma affine. TPQ=8, QPB=32, LDS scan, M in LDS, (256,4).
// NOTE: no min-waves hint > 4 — VGPR caps below demand spill wholesale
// (R6/R8: WRITE_SIZE 16->76/108 MB).
// ---------------------------------------------------------------------------
__global__ __launch_bounds__(QPB * TPQ, 4) void conv_knn(
    const float4* __restrict__ spk_g, const int* __restrict__ cstart_g,
    const float* __restrict__ Meff, float* __restrict__ out) {
  __shared__ __align__(16) float4 spk[N_];    // 16 KB (x, y, keybits, 0)
  __shared__ int    cstart[G_ * G_ + 1];      // 1 KB
  __shared__ __align__(16) float smem[NFEAT * H_];  // 22 KB: M

  const int b = blockIdx.y, tid = threadIdx.x;
  const int q = tid >> 3, t = tid & 7;
  const int s = blockIdx.x * QPB + q;
  const bool valid = (s < N_);

  const float4* spg = spk_g + (size_t)b * N_;
  for (int i = tid; i < N_; i += QPB * TPQ) spk[i] = spg[i];
  for (int i = tid; i < G_ * G_ + 1; i += QPB * TPQ)
    cstart[i] = cstart_g[b * (G_ * G_ + 1) + i];
  __syncthreads();

  float px = 0.f, py = 0.f;
  int cx = 0, cy = 0;
  if (valid) {
    px = spk[s].x; py = spk[s].y;
    cx = min(G_ - 1, max(0, (int)(px * (float)G_)));
    cy = min(G_ - 1, max(0, (int)(py * (float)G_)));
  }

  unsigned long long bk[K_];
#pragma unroll
  for (int k = 0; k < K_; ++k) bk[k] = ~0ull;

  // ---- single-pass 5x5 box scan, 8-way sliced per query ----
  const int X0 = max(cx - RING0, 0), X1 = min(cx + RING0, G_ - 1);
  const int Y0 = max(cy - RING0, 0), Y1 = min(cy + RING0, G_ - 1);
  if (valid) {
    for (int yy = Y0; yy <= Y1; ++yy) {
      const int s0 = cstart[yy * G_ + X0];
      const int s1 = cstart[yy * G_ + X1 + 1];
      for (int j = s0 + t; j < s1; j += TPQ) INSERT_LDS(j);
    }
  }

  // ---- fused merge + gather (unguarded: all 64 lanes shuffle) ----
  float feat[NFEAT];
  unsigned long long tenth = ~0ull;
  MERGE_GATHER(tenth);

  // ---- exact termination test (identical across a query's 8 lanes) ----
  bool done = true;
  if (valid) {
    const bool have10 = (tenth != ~0ull);
    const float tau = __uint_as_float((unsigned)(tenth >> 32));
    float R = 1e30f;
    if (X0 > 0)      R = fminf(R, px - (float)X0 * CW);
    if (X1 < G_ - 1) R = fminf(R, (float)(X1 + 1) * CW - px);
    if (Y0 > 0)      R = fminf(R, py - (float)Y0 * CW);
    if (Y1 < G_ - 1) R = fminf(R, (float)(Y1 + 1) * CW - py);
    const bool fullg = (X0 == 0) && (X1 == G_ - 1) && (Y0 == 0) && (Y1 == G_ - 1);
    const float Rs = R - 1e-6f;   // margin vs. cell-assignment rounding
    done = fullg || (have10 && Rs > 0.f && tau < Rs * Rs);
  }

  // ---- rare exact retry: full scan + re-merge (query-uniform predicate) ----
  if (__syncthreads_and(done ? 1 : 0) == 0) {
    const bool redo = valid && !done;
    if (redo) {
#pragma unroll
      for (int k = 0; k < K_; ++k) bk[k] = ~0ull;
      for (int j = t; j < N_; j += TPQ) INSERT_LDS(j);
    }
    if (redo) {          // all 8 lanes of a redo query enter together
      unsigned long long tenth2;
      MERGE_GATHER(tenth2);
    }
  }

  // ---- load M into LDS ----
  for (int i = tid; i < NFEAT * H_; i += QPB * TPQ) smem[i] = Meff[i];

  // ---- in-place stable bubble sorts on feat (all lanes redundant) ----
  if (valid) {
    // sort pairs (feat[2k],feat[2k+1]) by x  (strict swap => stable)
#pragma unroll
    for (int p = 0; p < K_ - 1; ++p) {
#pragma unroll
      for (int u = 0; u < K_ - 1 - p; ++u) {
        const bool sw = feat[2 * u + 2] < feat[2 * u];
        const float ax = feat[2 * u], ay = feat[2 * u + 1];
        feat[2 * u]     = sw ? feat[2 * u + 2] : ax;
        feat[2 * u + 1] = sw ? feat[2 * u + 3] : ay;
        feat[2 * u + 2] = sw ? ax : feat[2 * u + 2];
        feat[2 * u + 3] = sw ? ay : feat[2 * u + 3];
      }
    }
    // sort pairs (feat[20+2k],feat[20+2k+1]) by y
#pragma unroll
    for (int p = 0; p < K_ - 1; ++p) {
#pragma unroll
      for (int u = 0; u < K_ - 1 - p; ++u) {
        const int e = 20 + 2 * u;
        const bool sw = feat[e + 3] < feat[e + 1];
        const float ax = feat[e], ay = feat[e + 1];
        feat[e]     = sw ? feat[e + 2] : ax;
        feat[e + 1] = sw ? feat[e + 3] : ay;
        feat[e + 2] = sw ? ax : feat[e + 2];
        feat[e + 3] = sw ? ay : feat[e + 3];
      }
    }
    feat[40] = px;
    feat[41] = py;
    feat[42] = 1.f;
  }
  __syncthreads();

  // ---- fused affine: float4 LDS reads, g = j*32 + 4t (8 lanes span all 32
  // banks, queries broadcast); packed v_pk_fma_f32 accumulate;
  // 128B-contiguous stores ----
  if (valid) {
    const int otar = __float_as_int(spk[s].z) >> 16;
    float* op = out + ((size_t)(b * N_ + otar)) * H_;
    const float4* M4 = (const float4*)smem;   // row r = 32 float4
#pragma unroll
    for (int j = 0; j < 4; ++j) {
      v2f a0 = {0.f, 0.f}, a1 = {0.f, 0.f};
#pragma unroll
      for (int r = 0; r < NFEAT; ++r) {
        const float4 m = M4[r * 32 + j * 8 + t];
        const float f = feat[r];
#ifdef HAVE_EW_FMA
        const v2f ff = {f, f};
        const v2f m0 = {m.x, m.y};
        const v2f m1 = {m.z, m.w};
        a0 = __builtin_elementwise_fma(ff, m0, a0);
        a1 = __builtin_elementwise_fma(ff, m1, a1);
#else
        a0.x = fmaf(f, m.x, a0.x);
        a0.y = fmaf(f, m.y, a0.y);
        a1.x = fmaf(f, m.z, a1.x);
        a1.y = fmaf(f, m.w, a1.y);
#endif
      }
      *(float4*)&op[j * 32 + 4 * t] = make_float4(a0.x, a0.y, a1.x, a1.y);
    }
  }
}
#undef INSERT_LDS
#undef MERGE_GATHER

// ---------------------------------------------------------------------------
// No-workspace fallback (round-2 kernel).
// ---------------------------------------------------------------------------
#define LSTRIDE 170
__global__ __launch_bounds__(256, 4) void conv_emb_fb(
    const float* __restrict__ x, const float* __restrict__ Meff,
    float* __restrict__ out) {
  __shared__ float2 pts[N_];
  __shared__ float  smem[NFEAT * H_];
  __shared__ int    midx[32 * K_];

  const int b   = blockIdx.y;
  const int tid = threadIdx.x;
  const int q   = tid >> 3;
  const int t   = tid & 7;
  const int n   = blockIdx.x * 32 + q;
  const bool valid = (n < N_);

  const float2* xb = (const float2*)(x + (size_t)b * N_ * C_);
  for (int i = tid; i < N_; i += 256) pts[i] = xb[i];
  __syncthreads();

  float px = 0.f, py = 0.f;
  if (valid) { px = pts[n].x; py = pts[n].y; }

  float bd[K_]; int bi[K_];
#pragma unroll
  for (int k = 0; k < K_; ++k) { bd[k] = FLT_MAX; bi[k] = 0; }

#pragma unroll 2
  for (int m = 0; m < N_ / 8; ++m) {
    const int j = t + m * 8;
    const float2 p = pts[j];
    const float dx = __fsub_rn(px, p.x);
    const float dy = __fsub_rn(py, p.y);
    const float d  = __fadd_rn(__fmul_rn(dx, dx), __fmul_rn(dy, dy));
    bool c[K_];
#pragma unroll
    for (int s = 0; s < K_; ++s) c[s] = d < bd[s];
#pragma unroll
    for (int s = K_ - 1; s >= 1; --s) {
      bd[s] = c[s - 1] ? bd[s - 1] : (c[s] ? d : bd[s]);
      bi[s] = c[s - 1] ? bi[s - 1] : (c[s] ? j : bi[s]);
    }
    bd[0] = c[0] ? d : bd[0];
    bi[0] = c[0] ? j : bi[0];
  }

  const int lbase = q * LSTRIDE + t * 2 * K_;
#pragma unroll
  for (int e = 0; e < K_; ++e) {
    smem[lbase + 2 * e]     = bd[e];
    smem[lbase + 2 * e + 1] = __int_as_float(bi[e]);
  }
  __syncthreads();

  if (t == 0 && valid) {
    int cc[8];
#pragma unroll
    for (int tt = 0; tt < 8; ++tt) cc[tt] = 0;
    const int mb = q * LSTRIDE;
#pragma unroll
    for (int s = 0; s < K_; ++s) {
      float bdv = FLT_MAX; int biv = 0x7fffffff; int bt = 0;
#pragma unroll
      for (int tt = 0; tt < 8; ++tt) {
        const int off = mb + tt * 2 * K_ + cc[tt] * 2;
        const float hd = smem[off];
        const int   hi = __float_as_int(smem[off + 1]);
        const bool take = (hd < bdv) || ((hd == bdv) && (hi < biv));
        bdv = take ? hd : bdv;
        biv = take ? hi : biv;
        bt  = take ? tt : bt;
      }
      midx[q * K_ + s] = biv;
#pragma unroll
      for (int tt = 0; tt < 8; ++tt) cc[tt] += (bt == tt) ? 1 : 0;
    }
  }
  __syncthreads();

  int ridx[K_];
  if (valid) {
#pragma unroll
    for (int k = 0; k < K_; ++k) ridx[k] = midx[q * K_ + k];
  }
  for (int i = tid; i < NFEAT * H_; i += 256) smem[i] = Meff[i];

  float feat[NFEAT];
  if (valid) {
#pragma unroll
    for (int k = 0; k < K_; ++k) {
      const float2 c = pts[ridx[k]];
      feat[2 * k]          = c.x;
      feat[2 * k + 1]      = c.y;
      feat[20 + 2 * k]     = c.x;
      feat[20 + 2 * k + 1] = c.y;
    }
#pragma unroll
    for (int p = 0; p < K_ - 1; ++p) {
#pragma unroll
      for (int u = 0; u < K_ - 1 - p; ++u) {
        const bool sw = feat[2 * u + 2] < feat[2 * u];
        const float ax = feat[2 * u], ay = feat[2 * u + 1];
        feat[2 * u]     = sw ? feat[2 * u + 2] : ax;
        feat[2 * u + 1] = sw ? feat[2 * u + 3] : ay;
        feat[2 * u + 2] = sw ? ax : feat[2 * u + 2];
        feat[2 * u + 3] = sw ? ay : feat[2 * u + 3];
      }
    }
#pragma unroll
    for (int p = 0; p < K_ - 1; ++p) {
#pragma unroll
      for (int u = 0; u < K_ - 1 - p; ++u) {
        const int e = 20 + 2 * u;
        const bool sw = feat[e + 3] < feat[e + 1];
        const float ax = feat[e], ay = feat[e + 1];
        feat[e]     = sw ? feat[e + 2] : ax;
        feat[e + 1] = sw ? feat[e + 3] : ay;
        feat[e + 2] = sw ? ax : feat[e + 2];
        feat[e + 3] = sw ? ay : feat[e + 3];
      }
    }
    feat[40] = px;
    feat[41] = py;
    feat[42] = 1.f;
  }
  __syncthreads();

  if (valid) {
    float* op = out + ((size_t)(b * N_ + n)) * H_;
#pragma unroll 2
    for (int gi = 0; gi < H_ / 8; ++gi) {
      const int g = gi * 8 + t;
      float acc = 0.f;
#pragma unroll
      for (int r = 0; r < NFEAT; ++r)
        acc = fmaf(feat[r], smem[r * H_ + g], acc);
      op[g] = acc;
    }
  }
}

extern "C" void kernel_launch(void* const* d_in, const int* in_sizes, int n_in,
                              void* d_out, int out_size, void* d_ws, size_t ws_size,
                              hipStream_t stream) {
  const float* x  = (const float*)d_in[0];
  const float* Wx = (const float*)d_in[1];
  const float* bx = (const float*)d_in[2];
  const float* Wy = (const float*)d_in[3];
  const float* by = (const float*)d_in[4];
  const float* W1 = (const float*)d_in[5];
  const float* b1 = (const float*)d_in[6];
  const float* W2 = (const float*)d_in[7];
  const float* b2 = (const float*)d_in[8];
  float* o = (float*)d_out;

  char* ws = (char*)d_ws;
  float*  Meff     = (float*)(ws + WS_MEFF);
  float4* spk_g    = (float4*)(ws + WS_SPK);
  int*    cstart_g = (int*)(ws + WS_CSTART);

  if (ws_size >= (size_t)WS_NEED) {
    prep<<<dim3(B_ + NFEAT), dim3(256), 0, stream>>>(
        x, Wx, bx, Wy, by, W1, b1, W2, b2, Meff, spk_g, cstart_g);
    conv_knn<<<dim3((N_ + QPB - 1) / QPB, B_), dim3(QPB * TPQ), 0, stream>>>(
        spk_g, cstart_g, Meff, o);
  } else {
    build_meff<<<dim3(NFEAT), dim3(H_), 0, stream>>>(Wx, bx, Wy, by, W1, b1, W2, b2, Meff);
    conv_emb_fb<<<dim3((N_ + 31) / 32, B_), dim3(256), 0, stream>>>(x, Meff, o);
  }
}